// Round 1
// baseline (4905.942 us; speedup 1.0000x reference)
//
#include <hip/hip_runtime.h>

// ---------------- constants ----------------
#define S_LEN 2048
#define NH 32
#define NKV 8
#define HD 128
#define DMODEL 4096
#define MROWS 4096  // B*S

typedef short s16x8 __attribute__((ext_vector_type(8)));
typedef float fx4 __attribute__((ext_vector_type(4)));

__device__ __forceinline__ unsigned short f2bf(float f) {
  unsigned int u = __float_as_uint(f);
  u += 0x7fffu + ((u >> 16) & 1u);   // round-to-nearest-even
  return (unsigned short)(u >> 16);
}
__device__ __forceinline__ float bf2f(unsigned short h) {
  return __uint_as_float(((unsigned int)h) << 16);
}

#define GLDS16(gp, lp)                                                        \
  __builtin_amdgcn_global_load_lds(                                           \
      (const __attribute__((address_space(1))) void*)(gp),                    \
      (__attribute__((address_space(3))) void*)(lp), 16, 0, 0)

// ---------------- f32 -> bf16 cast ----------------
__global__ __launch_bounds__(256) void cast_k(const float* __restrict__ in,
                                              unsigned short* __restrict__ out,
                                              int n4) {
  int i = blockIdx.x * 256 + threadIdx.x;
  if (i >= n4) return;
  float4 v = *(const float4*)(in + (size_t)i * 4);
  ushort4 o;
  o.x = f2bf(v.x); o.y = f2bf(v.y); o.z = f2bf(v.z); o.w = f2bf(v.w);
  *(ushort4*)(out + (size_t)i * 4) = o;
}

// ---------------- bf16 GEMM: C[M,N] = A[M,K] * Bt[N,K]^T ----------------
// 128x128 tile, 4 waves (2x2 of 64x64), 16x16x32 MFMA, BK=32,
// global_load_lds(16B) staging, 2 barriers per K-step (m97 structure).
__global__ __launch_bounds__(256) void gemm_bt(const unsigned short* __restrict__ A,
                                               const unsigned short* __restrict__ Bt,
                                               float* __restrict__ Cf,
                                               unsigned short* __restrict__ Cb,
                                               int M, int N, int K, int bf16out) {
  __shared__ unsigned short As[128 * 32];
  __shared__ unsigned short Bs[128 * 32];
  const int tid = threadIdx.x;
  const int lane = tid & 63;
  const int w = tid >> 6;
  const int ntn = N >> 7;
  const int tm = blockIdx.x / ntn;
  const int tn = blockIdx.x % ntn;
  const int wm = (w >> 1) << 6;
  const int wn = (w & 1) << 6;

  // staging: chunk c = rr*256+tid covers As[row=c>>2][k=(c&3)*8 .. +8]
  const int sr = tid >> 2;
  const int kc = (tid & 3) << 3;
  const unsigned short* Ag = A + (size_t)(tm * 128 + sr) * K + kc;
  const unsigned short* Bg = Bt + (size_t)(tn * 128 + sr) * K + kc;
  unsigned short* lA = As + tid * 8;
  unsigned short* lB = Bs + tid * 8;
  const size_t half = (size_t)64 * K;

  fx4 acc[4][4] = {};

  const int opr = lane & 15;          // operand row (m or n within 16)
  const int opk = (lane >> 4) << 3;   // operand k offset: 0,8,16,24

  for (int k0 = 0; k0 < K; k0 += 32) {
    GLDS16(Ag + k0, lA);
    GLDS16(Ag + half + k0, lA + 2048);
    GLDS16(Bg + k0, lB);
    GLDS16(Bg + half + k0, lB + 2048);
    __syncthreads();  // drains vmcnt -> staged data visible
    s16x8 af[4], bf[4];
#pragma unroll
    for (int i = 0; i < 4; ++i)
      af[i] = *(const s16x8*)(As + (wm + i * 16 + opr) * 32 + opk);
#pragma unroll
    for (int j = 0; j < 4; ++j)
      bf[j] = *(const s16x8*)(Bs + (wn + j * 16 + opr) * 32 + opk);
#pragma unroll
    for (int i = 0; i < 4; ++i)
#pragma unroll
      for (int j = 0; j < 4; ++j)
        acc[i][j] = __builtin_amdgcn_mfma_f32_16x16x32_bf16(af[i], bf[j], acc[i][j], 0, 0, 0);
    __syncthreads();  // protect LDS from next-iter staging
  }

  // C/D layout (m89-verified): col = lane&15, row = (lane>>4)*4 + reg
  const int cm = (lane >> 4) << 2;
  const int cn = lane & 15;
#pragma unroll
  for (int i = 0; i < 4; ++i)
#pragma unroll
    for (int j = 0; j < 4; ++j) {
      int row = tm * 128 + wm + i * 16 + cm;
      int col = tn * 128 + wn + j * 16 + cn;
#pragma unroll
      for (int r = 0; r < 4; ++r) {
        float v = acc[i][j][r];
        if (bf16out) Cb[(size_t)(row + r) * N + col] = f2bf(v);
        else         Cf[(size_t)(row + r) * N + col] = v;
      }
    }
}

// ---------------- RoPE (interleaved pairs), in-place on bf16 Q and K ----------------
// one thread per (row, head, d-pair); total = MROWS * (NH+NKV) * 64
__global__ __launch_bounds__(256) void rope_k(unsigned short* __restrict__ q,
                                              unsigned short* __restrict__ k,
                                              const float* __restrict__ freqs,
                                              const int* __restrict__ pos) {
  int idx = blockIdx.x * 256 + threadIdx.x;
  int d2 = idx & 63;
  int t = idx >> 6;      // row*(NH+NKV) + hh
  int hh = t % (NH + NKV);
  int row = t / (NH + NKV);
  int s = row & (S_LEN - 1);
  float ang = freqs[((size_t)(pos[0] + s) << 6) + d2];
  float sv, cv;
  sincosf(ang, &sv, &cv);
  unsigned short* p;
  if (hh < NH) p = q + (size_t)row * DMODEL + hh * HD + (d2 << 1);
  else         p = k + (size_t)row * (NKV * HD) + (hh - NH) * HD + (d2 << 1);
  unsigned int xy = *(unsigned int*)p;
  float x1 = bf2f((unsigned short)(xy & 0xffffu));
  float x2 = bf2f((unsigned short)(xy >> 16));
  float o1 = x1 * cv - x2 * sv;
  float o2 = x1 * sv + x2 * cv;
  *(unsigned int*)p = (unsigned int)f2bf(o1) | ((unsigned int)f2bf(o2) << 16);
}

// ---------------- vector flash attention (no mask, full softmax over S) ----------------
// block = 256 thr = 4 waves; block owns (b, h, 16 q-rows); wave owns 4 rows.
// 64-key tiles staged in LDS; lane owns key for QK^T, lane owns 2 d-values for PV.
__global__ __launch_bounds__(256) void attn_vec(const unsigned short* __restrict__ qb,
                                                const unsigned short* __restrict__ kb,
                                                const unsigned short* __restrict__ vb,
                                                unsigned short* __restrict__ aob) {
  __shared__ float Qs[16][128];            // 8 KB
  __shared__ unsigned short Ks[64][132];   // padded: 264B rows (b64-aligned)
  __shared__ unsigned short Vs[64][132];
  __shared__ float Ps[4][64][4];           // [wave][key][row]

  const int tid = threadIdx.x;
  const int lane = tid & 63;
  const int w = tid >> 6;
  const int nqc = S_LEN / 16;  // 128
  const int qc = blockIdx.x % nqc;
  const int bh = blockIdx.x / nqc;
  const int h = bh & (NH - 1);
  const int b = bh >> 5;
  const int kv = h >> 2;

  {  // stage Q tile (bf16 -> f32), 8 elems/thread
    const int r = tid >> 4;
    const int c = (tid & 15) << 3;
    const unsigned short* src = qb + ((size_t)(b * S_LEN + qc * 16 + r)) * DMODEL + h * HD + c;
    ushort4 u0 = *(const ushort4*)src;
    ushort4 u1 = *(const ushort4*)(src + 4);
    Qs[r][c + 0] = bf2f(u0.x); Qs[r][c + 1] = bf2f(u0.y);
    Qs[r][c + 2] = bf2f(u0.z); Qs[r][c + 3] = bf2f(u0.w);
    Qs[r][c + 4] = bf2f(u1.x); Qs[r][c + 5] = bf2f(u1.y);
    Qs[r][c + 6] = bf2f(u1.z); Qs[r][c + 7] = bf2f(u1.w);
  }

  float mr[4], lr[4], o0[4], o1[4];
#pragma unroll
  for (int r = 0; r < 4; ++r) { mr[r] = -1e30f; lr[r] = 0.f; o0[r] = 0.f; o1[r] = 0.f; }
  const float scale = 0.08838834764831845f;  // 1/sqrt(128)

  for (int t0 = 0; t0 < S_LEN; t0 += 64) {
    __syncthreads();  // prev tile fully consumed (also covers Q-stage on iter 0)
#pragma unroll
    for (int rr = 0; rr < 8; ++rr) {  // stage K,V: 64x128 bf16 each
      int c = rr * 256 + tid;
      int row = c >> 5;
      int col = (c & 31) << 2;
      size_t g = ((size_t)(b * S_LEN + t0 + row)) * (NKV * HD) + kv * HD + col;
      *(ushort4*)&Ks[row][col] = *(const ushort4*)(kb + g);
      *(ushort4*)&Vs[row][col] = *(const ushort4*)(vb + g);
    }
    __syncthreads();

    // QK^T: lane owns key (t0+lane)
    float dot[4] = {0.f, 0.f, 0.f, 0.f};
    for (int d4 = 0; d4 < HD; d4 += 4) {
      ushort4 kk = *(const ushort4*)&Ks[lane][d4];
      float k0v = bf2f(kk.x), k1v = bf2f(kk.y), k2v = bf2f(kk.z), k3v = bf2f(kk.w);
#pragma unroll
      for (int r = 0; r < 4; ++r) {
        float4 qv = *(const float4*)&Qs[w * 4 + r][d4];
        dot[r] = fmaf(qv.x, k0v, dot[r]);
        dot[r] = fmaf(qv.y, k1v, dot[r]);
        dot[r] = fmaf(qv.z, k2v, dot[r]);
        dot[r] = fmaf(qv.w, k3v, dot[r]);
      }
    }
    // online softmax update
#pragma unroll
    for (int r = 0; r < 4; ++r) {
      float sc = dot[r] * scale;
      float tm = sc;
#pragma unroll
      for (int off = 32; off > 0; off >>= 1) tm = fmaxf(tm, __shfl_xor(tm, off));
      float mnew = fmaxf(mr[r], tm);
      float p = __expf(sc - mnew);
      float ts = p;
#pragma unroll
      for (int off = 32; off > 0; off >>= 1) ts += __shfl_xor(ts, off);
      float alpha = __expf(mr[r] - mnew);
      mr[r] = mnew;
      lr[r] = lr[r] * alpha + ts;
      o0[r] *= alpha; o1[r] *= alpha;
      Ps[w][lane][r] = p;  // wave-private; intra-wave lgkmcnt ordering suffices
    }
    // PV: lane owns d = {2*lane, 2*lane+1}
    for (int t = 0; t < 64; ++t) {
      float4 p4 = *(const float4*)&Ps[w][t][0];
      unsigned int v2 = *(const unsigned int*)&Vs[t][lane << 1];
      float vx = bf2f((unsigned short)(v2 & 0xffffu));
      float vy = bf2f((unsigned short)(v2 >> 16));
      o0[0] = fmaf(p4.x, vx, o0[0]); o1[0] = fmaf(p4.x, vy, o1[0]);
      o0[1] = fmaf(p4.y, vx, o0[1]); o1[1] = fmaf(p4.y, vy, o1[1]);
      o0[2] = fmaf(p4.z, vx, o0[2]); o1[2] = fmaf(p4.z, vy, o1[2]);
      o0[3] = fmaf(p4.w, vx, o0[3]); o1[3] = fmaf(p4.w, vy, o1[3]);
    }
  }
#pragma unroll
  for (int r = 0; r < 4; ++r) {
    float inv = 1.0f / lr[r];
    size_t g = ((size_t)(b * S_LEN + qc * 16 + w * 4 + r)) * DMODEL + h * HD + (lane << 1);
    unsigned int o = (unsigned int)f2bf(o0[r] * inv) | ((unsigned int)f2bf(o1[r] * inv) << 16);
    *(unsigned int*)(aob + g) = o;
  }
}

// ---------------- launch ----------------
extern "C" void kernel_launch(void* const* d_in, const int* in_sizes, int n_in,
                              void* d_out, int out_size, void* d_ws, size_t ws_size,
                              hipStream_t stream) {
  const float* hs = (const float*)d_in[0];
  const float* fr = (const float*)d_in[1];
  const float* Wq = (const float*)d_in[2];
  const float* Wk = (const float*)d_in[3];
  const float* Wv = (const float*)d_in[4];
  const float* Wo = (const float*)d_in[5];
  const int* pos = (const int*)d_in[6];
  float* out = (float*)d_out;

  // workspace layout (bf16 elems). total = 83,886,080 elems = 167.8 MB
  unsigned short* w = (unsigned short*)d_ws;
  unsigned short* hsb = w; w += 16777216;  // [4096,4096]
  unsigned short* wqb = w; w += 16777216;  // [4096,4096]  (reused as attn-out later)
  unsigned short* wob = w; w += 16777216;  // [4096,4096]
  unsigned short* qb  = w; w += 16777216;  // [4096,4096]  Q (rope in-place)
  unsigned short* wkb = w; w += 4194304;   // [1024,4096]
  unsigned short* wvb = w; w += 4194304;   // [1024,4096]
  unsigned short* kb  = w; w += 4194304;   // [4096,1024]  K (rope in-place)
  unsigned short* vb  = w; w += 4194304;   // [4096,1024]  V
  unsigned short* aob = wqb;               // alias: wqb dead after Q-projection

  if (ws_size < (size_t)83886080 * 2) return;  // no-op -> diagnosable absmax

  cast_k<<<16384, 256, 0, stream>>>(hs, hsb, 4194304);
  cast_k<<<16384, 256, 0, stream>>>(Wq, wqb, 4194304);
  cast_k<<<4096, 256, 0, stream>>>(Wk, wkb, 1048576);
  cast_k<<<4096, 256, 0, stream>>>(Wv, wvb, 1048576);
  cast_k<<<16384, 256, 0, stream>>>(Wo, wob, 4194304);

  gemm_bt<<<1024, 256, 0, stream>>>(hsb, wqb, nullptr, qb, MROWS, 4096, 4096, 1);
  gemm_bt<<<256, 256, 0, stream>>>(hsb, wkb, nullptr, kb, MROWS, 1024, 4096, 1);
  gemm_bt<<<256, 256, 0, stream>>>(hsb, wvb, nullptr, vb, MROWS, 1024, 4096, 1);

  rope_k<<<40960, 256, 0, stream>>>(qb, kb, fr, pos);  // 4096*40*64 threads

  attn_vec<<<8192, 256, 0, stream>>>(qb, kb, vb, aob);

  gemm_bt<<<1024, 256, 0, stream>>>(aob, wob, out, nullptr, MROWS, 4096, 4096, 0);
}

// Round 2
// 982.029 us; speedup vs baseline: 4.9957x; 4.9957x over previous
//
#include <hip/hip_runtime.h>

// ---------------- constants ----------------
#define S_LEN 2048
#define NH 32
#define NKV 8
#define HD 128
#define DMODEL 4096
#define MROWS 4096  // B*S

typedef short s16x8 __attribute__((ext_vector_type(8)));
typedef float fx4 __attribute__((ext_vector_type(4)));

__device__ __forceinline__ unsigned short f2bf(float f) {
  unsigned int u = __float_as_uint(f);
  u += 0x7fffu + ((u >> 16) & 1u);   // round-to-nearest-even
  return (unsigned short)(u >> 16);
}
__device__ __forceinline__ float bf2f(unsigned short h) {
  return __uint_as_float(((unsigned int)h) << 16);
}

#define GLDS16(gp, lp)                                                        \
  __builtin_amdgcn_global_load_lds(                                           \
      (const __attribute__((address_space(1))) void*)(gp),                    \
      (__attribute__((address_space(3))) void*)(lp), 16, 0, 0)

// ---------------- f32 -> bf16 cast ----------------
__global__ __launch_bounds__(256) void cast_k(const float* __restrict__ in,
                                              unsigned short* __restrict__ out,
                                              int n4) {
  int i = blockIdx.x * 256 + threadIdx.x;
  if (i >= n4) return;
  float4 v = *(const float4*)(in + (size_t)i * 4);
  ushort4 o;
  o.x = f2bf(v.x); o.y = f2bf(v.y); o.z = f2bf(v.z); o.w = f2bf(v.w);
  *(ushort4*)(out + (size_t)i * 4) = o;
}

// ---------------- bf16 GEMM: C[M,N] = A[M,K] * Bt[N,K]^T ----------------
__global__ __launch_bounds__(256) void gemm_bt(const unsigned short* __restrict__ A,
                                               const unsigned short* __restrict__ Bt,
                                               float* __restrict__ Cf,
                                               unsigned short* __restrict__ Cb,
                                               int M, int N, int K, int bf16out) {
  __shared__ unsigned short As[128 * 32];
  __shared__ unsigned short Bs[128 * 32];
  const int tid = threadIdx.x;
  const int lane = tid & 63;
  const int w = tid >> 6;
  const int ntn = N >> 7;
  const int tm = blockIdx.x / ntn;
  const int tn = blockIdx.x % ntn;
  const int wm = (w >> 1) << 6;
  const int wn = (w & 1) << 6;

  const int sr = tid >> 2;
  const int kc = (tid & 3) << 3;
  const unsigned short* Ag = A + (size_t)(tm * 128 + sr) * K + kc;
  const unsigned short* Bg = Bt + (size_t)(tn * 128 + sr) * K + kc;
  unsigned short* lA = As + tid * 8;
  unsigned short* lB = Bs + tid * 8;
  const size_t half = (size_t)64 * K;

  fx4 acc[4][4] = {};

  const int opr = lane & 15;
  const int opk = (lane >> 4) << 3;

  for (int k0 = 0; k0 < K; k0 += 32) {
    GLDS16(Ag + k0, lA);
    GLDS16(Ag + half + k0, lA + 2048);
    GLDS16(Bg + k0, lB);
    GLDS16(Bg + half + k0, lB + 2048);
    __syncthreads();
    s16x8 af[4], bf[4];
#pragma unroll
    for (int i = 0; i < 4; ++i)
      af[i] = *(const s16x8*)(As + (wm + i * 16 + opr) * 32 + opk);
#pragma unroll
    for (int j = 0; j < 4; ++j)
      bf[j] = *(const s16x8*)(Bs + (wn + j * 16 + opr) * 32 + opk);
#pragma unroll
    for (int i = 0; i < 4; ++i)
#pragma unroll
      for (int j = 0; j < 4; ++j)
        acc[i][j] = __builtin_amdgcn_mfma_f32_16x16x32_bf16(af[i], bf[j], acc[i][j], 0, 0, 0);
    __syncthreads();
  }

  const int cm = (lane >> 4) << 2;
  const int cn = lane & 15;
#pragma unroll
  for (int i = 0; i < 4; ++i)
#pragma unroll
    for (int j = 0; j < 4; ++j) {
      int row = tm * 128 + wm + i * 16 + cm;
      int col = tn * 128 + wn + j * 16 + cn;
#pragma unroll
      for (int r = 0; r < 4; ++r) {
        float v = acc[i][j][r];
        if (bf16out) Cb[(size_t)(row + r) * N + col] = f2bf(v);
        else         Cf[(size_t)(row + r) * N + col] = v;
      }
    }
}

// ---------------- bf16 matrix transpose: out[C][R] = in[R][C]^T ----------------
__global__ __launch_bounds__(256) void transpose_k(const unsigned short* __restrict__ in,
                                                   unsigned short* __restrict__ out,
                                                   int R, int C) {
  __shared__ unsigned short T[64][68];  // 136B rows: 4-way worst on reads, fine
  const int tid = threadIdx.x;
  const int nbc = C >> 6;
  const int br = blockIdx.x / nbc;
  const int bc = blockIdx.x % nbc;
  const int r0 = br << 6, c0 = bc << 6;
#pragma unroll
  for (int i = 0; i < 4; ++i) {
    int row = i * 16 + (tid >> 4);
    int col = (tid & 15) << 2;
    *(ushort4*)&T[row][col] = *(const ushort4*)(in + (size_t)(r0 + row) * C + c0 + col);
  }
  __syncthreads();
#pragma unroll
  for (int i = 0; i < 4; ++i) {
    int row = i * 16 + (tid >> 4);   // d index (col of in)
    int col = (tid & 15) << 2;       // t index (row of in)
    ushort4 v;
    v.x = T[col + 0][row]; v.y = T[col + 1][row];
    v.z = T[col + 2][row]; v.w = T[col + 3][row];
    *(ushort4*)(out + (size_t)(c0 + row) * R + r0 + col) = v;
  }
}

// ---------------- RoPE (interleaved pairs), in-place on bf16 Q and K ----------------
__global__ __launch_bounds__(256) void rope_k(unsigned short* __restrict__ q,
                                              unsigned short* __restrict__ k,
                                              const float* __restrict__ freqs,
                                              const int* __restrict__ pos) {
  int idx = blockIdx.x * 256 + threadIdx.x;
  int d2 = idx & 63;
  int t = idx >> 6;
  int hh = t % (NH + NKV);
  int row = t / (NH + NKV);
  int s = row & (S_LEN - 1);
  float ang = freqs[((size_t)(pos[0] + s) << 6) + d2];
  float sv, cv;
  sincosf(ang, &sv, &cv);
  unsigned short* p;
  if (hh < NH) p = q + (size_t)row * DMODEL + hh * HD + (d2 << 1);
  else         p = k + (size_t)row * (NKV * HD) + (hh - NH) * HD + (d2 << 1);
  unsigned int xy = *(unsigned int*)p;
  float x1 = bf2f((unsigned short)(xy & 0xffffu));
  float x2 = bf2f((unsigned short)(xy >> 16));
  float o1 = x1 * cv - x2 * sv;
  float o2 = x1 * sv + x2 * cv;
  *(unsigned int*)p = (unsigned int)f2bf(o1) | ((unsigned int)f2bf(o2) << 16);
}

// ---------------- MFMA flash attention ----------------
// block = 256 thr (4 waves); block owns (b, h, 64 q-rows); wave owns 16 q-rows.
// K-tile = 64 keys. Q/K staged [64][128] (256B rows), V^T staged [128][64]
// (128B rows), all XOR-swizzled (byte ^= (row&7)<<4) via pre-swizzled
// global_load_lds source addresses; reads apply the same XOR (2-way = free).
// P routed through wave-private padded LDS [16][72].
__global__ __launch_bounds__(256) void attn_mfma(const unsigned short* __restrict__ qb,
                                                 const unsigned short* __restrict__ kb,
                                                 const unsigned short* __restrict__ vtb,
                                                 unsigned short* __restrict__ aob) {
  __shared__ alignas(16) unsigned short Ks[64 * 128];    // 16 KB
  __shared__ alignas(16) unsigned short Vts[128 * 64];   // 16 KB
  __shared__ alignas(16) unsigned short Ps[4][16 * 72];  // 9 KB
  const int tid = threadIdx.x;
  const int lane = tid & 63;
  const int w = tid >> 6;
  const int qc = blockIdx.x & 31;        // 32 q-chunks of 64 rows
  const int bh = blockIdx.x >> 5;
  const int h = bh & 31;
  const int b = bh >> 5;
  const int kv = h >> 2;

  const int opr = lane & 15;             // operand row within 16
  const int opk2 = (lane >> 4) << 4;     // k-subblock byte offset: 0,16,32,48
  const int cm = (lane >> 4) << 2;       // C row base
  const int cn = lane & 15;              // C col

  // ---- stage Q tile (64x128) into Ks (swizzled), hoist a-frags to regs ----
  {
    const size_t qrow0 = (size_t)(b * S_LEN + qc * 64);
#pragma unroll
    for (int i = 0; i < 4; ++i) {
      int d = i * 4096 + tid * 16;
      int row = d >> 8;
      int colb = (d & 255) ^ ((row & 7) << 4);
      GLDS16(qb + (qrow0 + row) * DMODEL + h * HD + (colb >> 1), (char*)Ks + d);
    }
  }
  __syncthreads();
  s16x8 aq[4];
  {
    int qrow = w * 16 + opr;
    const char* base = (const char*)Ks + qrow * 256;
#pragma unroll
    for (int kk = 0; kk < 4; ++kk)
      aq[kk] = *(const s16x8*)(base + ((kk * 64 + opk2) ^ ((qrow & 7) << 4)));
  }

  float m_run[4], l_run[4];
  fx4 acc_o[8] = {};
#pragma unroll
  for (int r = 0; r < 4; ++r) { m_run[r] = -1e30f; l_run[r] = 0.f; }
  const float scale = 0.08838834764831845f;  // 1/sqrt(128)
  unsigned short* Pw = Ps[w];

  for (int t0 = 0; t0 < S_LEN; t0 += 64) {
    __syncthreads();  // prev-tile LDS reads done (covers Q-frag reads on iter 0)
    const size_t krow0 = (size_t)(b * S_LEN + t0);
#pragma unroll
    for (int i = 0; i < 4; ++i) {  // K tile [64][128]
      int d = i * 4096 + tid * 16;
      int row = d >> 8;
      int colb = (d & 255) ^ ((row & 7) << 4);
      GLDS16(kb + (krow0 + row) * (NKV * HD) + kv * HD + (colb >> 1), (char*)Ks + d);
    }
#pragma unroll
    for (int i = 0; i < 4; ++i) {  // V^T tile [128][64]
      int d = i * 4096 + tid * 16;
      int row = d >> 7;
      int colb = (d & 127) ^ ((row & 7) << 4);
      GLDS16(vtb + (size_t)(kv * HD + row) * MROWS + (size_t)(b * S_LEN + t0) + (colb >> 1),
             (char*)Vts + d);
    }
    __syncthreads();  // staged data visible (barrier drains vmcnt)

    // ---- QK^T: accs[jb] = Q(16) x K(16)^T over K=128 ----
    fx4 accs[4] = {};
#pragma unroll
    for (int jb = 0; jb < 4; ++jb) {
      int krow = jb * 16 + opr;
      const char* kbase = (const char*)Ks + krow * 256;
#pragma unroll
      for (int kk = 0; kk < 4; ++kk) {
        s16x8 bk = *(const s16x8*)(kbase + ((kk * 64 + opk2) ^ ((krow & 7) << 4)));
        accs[jb] = __builtin_amdgcn_mfma_f32_16x16x32_bf16(aq[kk], bk, accs[jb], 0, 0, 0);
      }
    }

    // ---- online softmax over this tile's 64 keys (rows = cm+reg) ----
    float p[4][4];       // [jb][reg]
    float mloc[4], psum[4], alpha[4];
#pragma unroll
    for (int r = 0; r < 4; ++r) {
      float a0 = accs[0][r] * scale, a1 = accs[1][r] * scale;
      float a2 = accs[2][r] * scale, a3 = accs[3][r] * scale;
      p[0][r] = a0; p[1][r] = a1; p[2][r] = a2; p[3][r] = a3;
      mloc[r] = fmaxf(fmaxf(a0, a1), fmaxf(a2, a3));
    }
#pragma unroll
    for (int off = 1; off <= 8; off <<= 1)
#pragma unroll
      for (int r = 0; r < 4; ++r) mloc[r] = fmaxf(mloc[r], __shfl_xor(mloc[r], off));
#pragma unroll
    for (int r = 0; r < 4; ++r) {
      float mnew = fmaxf(m_run[r], mloc[r]);
      alpha[r] = __expf(m_run[r] - mnew);
      m_run[r] = mnew;
      psum[r] = 0.f;
#pragma unroll
      for (int jb = 0; jb < 4; ++jb) {
        p[jb][r] = __expf(p[jb][r] - mnew);
        psum[r] += p[jb][r];
      }
    }
#pragma unroll
    for (int off = 1; off <= 8; off <<= 1)
#pragma unroll
      for (int r = 0; r < 4; ++r) psum[r] += __shfl_xor(psum[r], off);
#pragma unroll
    for (int r = 0; r < 4; ++r) l_run[r] = l_run[r] * alpha[r] + psum[r];
#pragma unroll
    for (int db = 0; db < 8; ++db)
#pragma unroll
      for (int r = 0; r < 4; ++r) acc_o[db][r] *= alpha[r];

    // ---- P (bf16) -> wave-private LDS, reload as A-frags ----
#pragma unroll
    for (int jb = 0; jb < 4; ++jb)
#pragma unroll
      for (int r = 0; r < 4; ++r)
        Pw[(cm + r) * 72 + jb * 16 + cn] = f2bf(p[jb][r]);
    s16x8 ap[2];
#pragma unroll
    for (int tb = 0; tb < 2; ++tb)
      ap[tb] = *(const s16x8*)((const char*)Pw + opr * 144 + tb * 64 + opk2);

    // ---- PV: acc_o[db] += P(16x64) x V^T(16x64)^T ----
#pragma unroll
    for (int db = 0; db < 8; ++db) {
      int vrow = db * 16 + opr;
      const char* vbase = (const char*)Vts + vrow * 128;
#pragma unroll
      for (int tb = 0; tb < 2; ++tb) {
        s16x8 bv = *(const s16x8*)(vbase + ((tb * 64 + opk2) ^ ((vrow & 7) << 4)));
        acc_o[db] = __builtin_amdgcn_mfma_f32_16x16x32_bf16(ap[tb], bv, acc_o[db], 0, 0, 0);
      }
    }
  }

  // ---- epilogue: normalize, write bf16 ----
  float inv[4];
#pragma unroll
  for (int r = 0; r < 4; ++r) inv[r] = 1.0f / l_run[r];
#pragma unroll
  for (int db = 0; db < 8; ++db)
#pragma unroll
    for (int r = 0; r < 4; ++r) {
      size_t row = (size_t)(b * S_LEN + qc * 64 + w * 16 + cm + r);
      aob[row * DMODEL + h * HD + db * 16 + cn] = f2bf(acc_o[db][r] * inv[r]);
    }
}

// ---------------- launch ----------------
extern "C" void kernel_launch(void* const* d_in, const int* in_sizes, int n_in,
                              void* d_out, int out_size, void* d_ws, size_t ws_size,
                              hipStream_t stream) {
  const float* hs = (const float*)d_in[0];
  const float* fr = (const float*)d_in[1];
  const float* Wq = (const float*)d_in[2];
  const float* Wk = (const float*)d_in[3];
  const float* Wv = (const float*)d_in[4];
  const float* Wo = (const float*)d_in[5];
  const int* pos = (const int*)d_in[6];
  float* out = (float*)d_out;

  unsigned short* w = (unsigned short*)d_ws;
  unsigned short* hsb = w; w += 16777216;  // [4096,4096]
  unsigned short* wqb = w; w += 16777216;  // [4096,4096]  (aliased as attn-out later)
  unsigned short* wob = w; w += 16777216;  // [4096,4096]
  unsigned short* qb  = w; w += 16777216;  // [4096,4096]  Q (rope in-place)
  unsigned short* wkb = w; w += 4194304;   // [1024,4096]  (aliased as V^T later)
  unsigned short* wvb = w; w += 4194304;   // [1024,4096]
  unsigned short* kb  = w; w += 4194304;   // [4096,1024]  K (rope in-place)
  unsigned short* vb  = w; w += 4194304;   // [4096,1024]  V
  unsigned short* aob = wqb;               // alias: wqb dead after Q-projection
  unsigned short* vtb = wkb;               // alias: wkb dead after K-projection

  if (ws_size < (size_t)83886080 * 2) return;

  cast_k<<<16384, 256, 0, stream>>>(hs, hsb, 4194304);
  cast_k<<<16384, 256, 0, stream>>>(Wq, wqb, 4194304);
  cast_k<<<4096, 256, 0, stream>>>(Wk, wkb, 1048576);
  cast_k<<<4096, 256, 0, stream>>>(Wv, wvb, 1048576);
  cast_k<<<16384, 256, 0, stream>>>(Wo, wob, 4194304);

  gemm_bt<<<1024, 256, 0, stream>>>(hsb, wqb, nullptr, qb, MROWS, 4096, 4096, 1);
  gemm_bt<<<256, 256, 0, stream>>>(hsb, wkb, nullptr, kb, MROWS, 1024, 4096, 1);
  gemm_bt<<<256, 256, 0, stream>>>(hsb, wvb, nullptr, vb, MROWS, 1024, 4096, 1);

  transpose_k<<<1024, 256, 0, stream>>>(vb, vtb, MROWS, 1024);  // V -> V^T [1024][4096]

  rope_k<<<40960, 256, 0, stream>>>(qb, kb, fr, pos);

  attn_mfma<<<2048, 256, 0, stream>>>(qb, kb, vtb, aob);

  gemm_bt<<<1024, 256, 0, stream>>>(aob, wob, out, nullptr, MROWS, 4096, 4096, 0);
}

// Round 5
// 889.577 us; speedup vs baseline: 5.5149x; 1.1039x over previous
//
#include <hip/hip_runtime.h>

// ---------------- constants ----------------
#define S_LEN 2048
#define NH 32
#define NKV 8
#define HD 128
#define DMODEL 4096
#define MROWS 4096   // B*S
#define QKVN 6144    // 4096 q + 1024 k + 1024 v output cols

typedef short s16x8 __attribute__((ext_vector_type(8)));
typedef float fx4 __attribute__((ext_vector_type(4)));

__device__ __forceinline__ unsigned short f2bf(float f) {
  unsigned int u = __float_as_uint(f);
  u += 0x7fffu + ((u >> 16) & 1u);   // round-to-nearest-even
  return (unsigned short)(u >> 16);
}
__device__ __forceinline__ float bf2f(unsigned short h) {
  return __uint_as_float(((unsigned int)h) << 16);
}

#define GLDS16(gp, lp)                                                        \
  __builtin_amdgcn_global_load_lds(                                           \
      (const __attribute__((address_space(1))) void*)(gp),                    \
      (__attribute__((address_space(3))) void*)(lp), 16, 0, 0)

#define MFMA16(a, b, c) __builtin_amdgcn_mfma_f32_16x16x32_bf16((a), (b), (c), 0, 0, 0)

// ---------------- fused f32 -> bf16 casts (all 5 tensors, one launch) ----------------
__global__ __launch_bounds__(256) void cast_all_k(const float* __restrict__ hs,
                                                  const float* __restrict__ Wq,
                                                  const float* __restrict__ Wk,
                                                  const float* __restrict__ Wv,
                                                  const float* __restrict__ Wo,
                                                  unsigned short* __restrict__ hsb,
                                                  unsigned short* __restrict__ wqkvb,
                                                  unsigned short* __restrict__ wob) {
  int i = blockIdx.x * 256 + threadIdx.x;
  const float* src;
  unsigned short* dst;
  int off;
  if (i < 4194304)       { src = hs; dst = hsb;                off = 0; }
  else if (i < 8388608)  { src = Wq; dst = wqkvb;              off = 4194304; }
  else if (i < 9437184)  { src = Wk; dst = wqkvb + 16777216;   off = 8388608; }
  else if (i < 10485760) { src = Wv; dst = wqkvb + 20971520;   off = 9437184; }
  else                   { src = Wo; dst = wob;                off = 10485760; }
  int j = i - off;
  float4 v = *(const float4*)(src + (size_t)j * 4);
  ushort4 o;
  o.x = f2bf(v.x); o.y = f2bf(v.y); o.z = f2bf(v.z); o.w = f2bf(v.w);
  *(ushort4*)(dst + (size_t)j * 4) = o;
}

// ---------------- bf16 GEMM: C[M,N] = A[M,K] * Bt[N,K]^T ----------------
// VERIFIED m97-structure (rounds 1-2) + bijective XCD block swizzle.
__global__ __launch_bounds__(256) void gemm_bt(const unsigned short* __restrict__ A,
                                               const unsigned short* __restrict__ Bt,
                                               float* __restrict__ Cf,
                                               unsigned short* __restrict__ Cb,
                                               int M, int N, int K, int bf16out) {
  __shared__ unsigned short As[128 * 32];
  __shared__ unsigned short Bs[128 * 32];
  const int tid = threadIdx.x;
  const int lane = tid & 63;
  const int w = tid >> 6;
  const int nwg = gridDim.x;
  const int wgs = (blockIdx.x & 7) * (nwg >> 3) + (blockIdx.x >> 3);  // XCD swizzle
  const int ntn = N >> 7;
  const int tm = wgs / ntn;
  const int tn = wgs % ntn;
  const int wm = (w >> 1) << 6;
  const int wn = (w & 1) << 6;

  const int sr = tid >> 2;
  const int kc = (tid & 3) << 3;
  const unsigned short* Ag = A + (size_t)(tm * 128 + sr) * K + kc;
  const unsigned short* Bg = Bt + (size_t)(tn * 128 + sr) * K + kc;
  unsigned short* lA = As + tid * 8;
  unsigned short* lB = Bs + tid * 8;
  const size_t half = (size_t)64 * K;

  fx4 acc[4][4] = {};

  const int opr = lane & 15;
  const int opk = (lane >> 4) << 3;

  for (int k0 = 0; k0 < K; k0 += 32) {
    GLDS16(Ag + k0, lA);
    GLDS16(Ag + half + k0, lA + 2048);
    GLDS16(Bg + k0, lB);
    GLDS16(Bg + half + k0, lB + 2048);
    __syncthreads();
    s16x8 af[4], bf[4];
#pragma unroll
    for (int i = 0; i < 4; ++i)
      af[i] = *(const s16x8*)(As + (wm + i * 16 + opr) * 32 + opk);
#pragma unroll
    for (int j = 0; j < 4; ++j)
      bf[j] = *(const s16x8*)(Bs + (wn + j * 16 + opr) * 32 + opk);
#pragma unroll
    for (int i = 0; i < 4; ++i)
#pragma unroll
      for (int j = 0; j < 4; ++j)
        acc[i][j] = MFMA16(af[i], bf[j], acc[i][j]);
    __syncthreads();
  }

  const int cm = (lane >> 4) << 2;
  const int cn = lane & 15;
#pragma unroll
  for (int i = 0; i < 4; ++i)
#pragma unroll
    for (int j = 0; j < 4; ++j) {
      int row = tm * 128 + wm + i * 16 + cm;
      int col = tn * 128 + wn + j * 16 + cn;
#pragma unroll
      for (int r = 0; r < 4; ++r) {
        float v = acc[i][j][r];
        if (bf16out) Cb[(size_t)(row + r) * N + col] = f2bf(v);
        else         Cf[(size_t)(row + r) * N + col] = v;
      }
    }
}

// ---------------- bf16 transpose: out[C][R] = in[R][C]^T (in rows strided) ----------------
__global__ __launch_bounds__(256) void transpose_k(const unsigned short* __restrict__ in,
                                                   unsigned short* __restrict__ out,
                                                   int R, int C, int istride) {
  __shared__ unsigned short T[64][68];
  const int tid = threadIdx.x;
  const int nbc = C >> 6;
  const int br = blockIdx.x / nbc;
  const int bc = blockIdx.x % nbc;
  const int r0 = br << 6, c0 = bc << 6;
#pragma unroll
  for (int i = 0; i < 4; ++i) {
    int row = i * 16 + (tid >> 4);
    int col = (tid & 15) << 2;
    *(ushort4*)&T[row][col] = *(const ushort4*)(in + (size_t)(r0 + row) * istride + c0 + col);
  }
  __syncthreads();
#pragma unroll
  for (int i = 0; i < 4; ++i) {
    int row = i * 16 + (tid >> 4);
    int col = (tid & 15) << 2;
    ushort4 v;
    v.x = T[col + 0][row]; v.y = T[col + 1][row];
    v.z = T[col + 2][row]; v.w = T[col + 3][row];
    *(ushort4*)(out + (size_t)(c0 + row) * R + r0 + col) = v;
  }
}

// ---------------- RoPE cos/sin table: tab[s*64+d] = (cos, sin) ----------------
__global__ __launch_bounds__(256) void rope_tab_k(const float* __restrict__ freqs,
                                                  const int* __restrict__ pos,
                                                  float2* __restrict__ tab) {
  int i = blockIdx.x * 256 + threadIdx.x;  // S*64 = 131072
  int s = i >> 6, d = i & 63;
  float ang = freqs[((size_t)(pos[0] + s) << 6) + d];
  float sv, cv;
  sincosf(ang, &sv, &cv);
  tab[i] = make_float2(cv, sv);
}

// ---------------- RoPE apply, in-place on merged qkv buffer (row stride QKVN) ----------------
__global__ __launch_bounds__(256) void rope_k(unsigned short* __restrict__ qkv,
                                              const float2* __restrict__ tab) {
  int idx = blockIdx.x * 256 + threadIdx.x;  // 4096 * 40 * 64
  int d2 = idx & 63;
  int t = idx >> 6;
  int hh = t % (NH + NKV);
  int row = t / (NH + NKV);
  int s = row & (S_LEN - 1);
  float2 cs = tab[(s << 6) + d2];
  unsigned short* p = qkv + (size_t)row * QKVN +
                      (hh < NH ? hh * HD : DMODEL + (hh - NH) * HD) + (d2 << 1);
  unsigned int xy = *(unsigned int*)p;
  float x1 = bf2f((unsigned short)(xy & 0xffffu));
  float x2 = bf2f((unsigned short)(xy >> 16));
  float o1 = x1 * cs.x - x2 * cs.y;
  float o2 = x1 * cs.y + x2 * cs.x;
  *(unsigned int*)p = (unsigned int)f2bf(o1) | ((unsigned int)f2bf(o2) << 16);
}

// ---------------- MFMA flash attention — ROUND-2 VERIFIED INTERNALS ----------------
// Only change vs the round-2 passing version: Q/K row strides are QKVN (merged
// qkv buffer). Softmax: per-16-lane-group reductions; P via scalar f2bf stores
// to unswizzled [16][72] LDS; l from f32 psum. (Round-3 softmax rework reverted
// for bisection.)
__global__ __launch_bounds__(256) void attn_mfma(const unsigned short* __restrict__ qb,
                                                 const unsigned short* __restrict__ kb,
                                                 const unsigned short* __restrict__ vtb,
                                                 unsigned short* __restrict__ aob) {
  __shared__ alignas(16) unsigned short Ks[64 * 128];    // 16 KB (swizzled)
  __shared__ alignas(16) unsigned short Vts[128 * 64];   // 16 KB (swizzled)
  __shared__ alignas(16) unsigned short Ps[4][16 * 72];  // 9 KB
  const int tid = threadIdx.x;
  const int lane = tid & 63;
  const int w = tid >> 6;
  const int qc = blockIdx.x & 31;        // 32 q-chunks of 64 rows
  const int bh = blockIdx.x >> 5;
  const int h = bh & 31;
  const int b = bh >> 5;
  const int kv = h >> 2;

  const int opr = lane & 15;             // operand row within 16
  const int opk2 = (lane >> 4) << 4;     // k-subblock byte offset: 0,16,32,48
  const int cm = (lane >> 4) << 2;       // C row base
  const int cn = lane & 15;              // C col

  // ---- stage Q tile (64x128) into Ks (swizzled), hoist a-frags to regs ----
  {
    const size_t qrow0 = (size_t)(b * S_LEN + qc * 64);
#pragma unroll
    for (int i = 0; i < 4; ++i) {
      int d = i * 4096 + tid * 16;
      int row = d >> 8;
      int colb = (d & 255) ^ ((row & 7) << 4);
      GLDS16(qb + (qrow0 + row) * QKVN + h * HD + (colb >> 1), (char*)Ks + d);
    }
  }
  __syncthreads();
  s16x8 aq[4];
  {
    int qrow = w * 16 + opr;
    const char* base = (const char*)Ks + qrow * 256;
#pragma unroll
    for (int kk = 0; kk < 4; ++kk)
      aq[kk] = *(const s16x8*)(base + ((kk * 64 + opk2) ^ ((qrow & 7) << 4)));
  }

  float m_run[4], l_run[4];
  fx4 acc_o[8] = {};
#pragma unroll
  for (int r = 0; r < 4; ++r) { m_run[r] = -1e30f; l_run[r] = 0.f; }
  const float scale = 0.08838834764831845f;  // 1/sqrt(128)
  unsigned short* Pw = Ps[w];

  for (int t0 = 0; t0 < S_LEN; t0 += 64) {
    __syncthreads();  // prev-tile LDS reads done (covers Q-frag reads on iter 0)
    const size_t krow0 = (size_t)(b * S_LEN + t0);
#pragma unroll
    for (int i = 0; i < 4; ++i) {  // K tile [64][128]
      int d = i * 4096 + tid * 16;
      int row = d >> 8;
      int colb = (d & 255) ^ ((row & 7) << 4);
      GLDS16(kb + (krow0 + row) * QKVN + kv * HD + (colb >> 1), (char*)Ks + d);
    }
#pragma unroll
    for (int i = 0; i < 4; ++i) {  // V^T tile [128][64]
      int d = i * 4096 + tid * 16;
      int row = d >> 7;
      int colb = (d & 127) ^ ((row & 7) << 4);
      GLDS16(vtb + (size_t)(kv * HD + row) * MROWS + (size_t)(b * S_LEN + t0) + (colb >> 1),
             (char*)Vts + d);
    }
    __syncthreads();  // staged data visible (barrier drains vmcnt)

    // ---- QK^T: accs[jb] = Q(16) x K(16)^T over K=128 ----
    fx4 accs[4] = {};
#pragma unroll
    for (int jb = 0; jb < 4; ++jb) {
      int krow = jb * 16 + opr;
      const char* kbase = (const char*)Ks + krow * 256;
#pragma unroll
      for (int kk = 0; kk < 4; ++kk) {
        s16x8 bk = *(const s16x8*)(kbase + ((kk * 64 + opk2) ^ ((krow & 7) << 4)));
        accs[jb] = MFMA16(aq[kk], bk, accs[jb]);
      }
    }

    // ---- online softmax over this tile's 64 keys (rows = cm+reg) ----
    float p[4][4];       // [jb][reg]
    float mloc[4], psum[4], alpha[4];
#pragma unroll
    for (int r = 0; r < 4; ++r) {
      float a0 = accs[0][r] * scale, a1 = accs[1][r] * scale;
      float a2 = accs[2][r] * scale, a3 = accs[3][r] * scale;
      p[0][r] = a0; p[1][r] = a1; p[2][r] = a2; p[3][r] = a3;
      mloc[r] = fmaxf(fmaxf(a0, a1), fmaxf(a2, a3));
    }
#pragma unroll
    for (int off = 1; off <= 8; off <<= 1)
#pragma unroll
      for (int r = 0; r < 4; ++r) mloc[r] = fmaxf(mloc[r], __shfl_xor(mloc[r], off));
#pragma unroll
    for (int r = 0; r < 4; ++r) {
      float mnew = fmaxf(m_run[r], mloc[r]);
      alpha[r] = __expf(m_run[r] - mnew);
      m_run[r] = mnew;
      psum[r] = 0.f;
#pragma unroll
      for (int jb = 0; jb < 4; ++jb) {
        p[jb][r] = __expf(p[jb][r] - mnew);
        psum[r] += p[jb][r];
      }
    }
#pragma unroll
    for (int off = 1; off <= 8; off <<= 1)
#pragma unroll
      for (int r = 0; r < 4; ++r) psum[r] += __shfl_xor(psum[r], off);
#pragma unroll
    for (int r = 0; r < 4; ++r) l_run[r] = l_run[r] * alpha[r] + psum[r];
#pragma unroll
    for (int db = 0; db < 8; ++db)
#pragma unroll
      for (int r = 0; r < 4; ++r) acc_o[db][r] *= alpha[r];

    // ---- P (bf16) -> wave-private LDS, reload as A-frags ----
#pragma unroll
    for (int jb = 0; jb < 4; ++jb)
#pragma unroll
      for (int r = 0; r < 4; ++r)
        Pw[(cm + r) * 72 + jb * 16 + cn] = f2bf(p[jb][r]);
    s16x8 ap[2];
#pragma unroll
    for (int tb = 0; tb < 2; ++tb)
      ap[tb] = *(const s16x8*)((const char*)Pw + opr * 144 + tb * 64 + opk2);

    // ---- PV: acc_o[db] += P(16x64) x V^T(16x64)^T ----
#pragma unroll
    for (int db = 0; db < 8; ++db) {
      int vrow = db * 16 + opr;
      const char* vbase = (const char*)Vts + vrow * 128;
#pragma unroll
      for (int tb = 0; tb < 2; ++tb) {
        s16x8 bv = *(const s16x8*)(vbase + ((tb * 64 + opk2) ^ ((vrow & 7) << 4)));
        acc_o[db] = MFMA16(ap[tb], bv, acc_o[db]);
      }
    }
  }

  // ---- epilogue: normalize, write bf16 ----
  float inv[4];
#pragma unroll
  for (int r = 0; r < 4; ++r) inv[r] = 1.0f / l_run[r];
#pragma unroll
  for (int db = 0; db < 8; ++db)
#pragma unroll
    for (int r = 0; r < 4; ++r) {
      size_t row = (size_t)(b * S_LEN + qc * 64 + w * 16 + cm + r);
      aob[row * DMODEL + h * HD + db * 16 + cn] = f2bf(acc_o[db][r] * inv[r]);
    }
}

// ---------------- launch ----------------
extern "C" void kernel_launch(void* const* d_in, const int* in_sizes, int n_in,
                              void* d_out, int out_size, void* d_ws, size_t ws_size,
                              hipStream_t stream) {
  const float* hs = (const float*)d_in[0];
  const float* fr = (const float*)d_in[1];
  const float* Wq = (const float*)d_in[2];
  const float* Wk = (const float*)d_in[3];
  const float* Wv = (const float*)d_in[4];
  const float* Wo = (const float*)d_in[5];
  const int* pos = (const int*)d_in[6];
  float* out = (float*)d_out;

  // workspace (bf16 elems), total 83,886,080 shorts = 167.8 MB
  unsigned short* w = (unsigned short*)d_ws;
  unsigned short* hsb   = w; w += 16777216;  // [4096,4096] hs bf16 (tab reuses after QKV gemm)
  unsigned short* wqkvb = w; w += 25165824;  // [6144,4096] Wq|Wk|Wv  (aob+vtb reuse after gemm)
  unsigned short* wob   = w; w += 16777216;  // [4096,4096]
  unsigned short* qkvb  = w; w += 25165824;  // [4096,6144] q|k|v per row (rope in-place)
  unsigned short* aob = wqkvb;               // [4096,4096] attn out
  unsigned short* vtb = wqkvb + 16777216;    // [1024,4096] V^T
  float2* tab = (float2*)hsb;                // [2048*64] cos/sin

  if (ws_size < (size_t)83886080 * 2) return;

  cast_all_k<<<57344, 256, 0, stream>>>(hs, Wq, Wk, Wv, Wo, hsb, wqkvb, wob);

  // fused QKV projection: [4096,4096] x [6144,4096]^T -> [4096,6144]
  gemm_bt<<<1536, 256, 0, stream>>>(hsb, wqkvb, nullptr, qkvb, MROWS, QKVN, DMODEL, 1);

  rope_tab_k<<<512, 256, 0, stream>>>(fr, pos, tab);   // hsb dead now
  rope_k<<<40960, 256, 0, stream>>>(qkvb, tab);

  transpose_k<<<1024, 256, 0, stream>>>(qkvb + 5120, vtb, MROWS, 1024, QKVN);  // V -> V^T

  attn_mfma<<<2048, 256, 0, stream>>>(qkvb, qkvb + 4096, vtb, aob);

  // output projection: [4096,4096] x [4096,4096]^T -> f32 out
  gemm_bt<<<1024, 256, 0, stream>>>(aob, wob, out, nullptr, MROWS, DMODEL, DMODEL, 0);
}